// Round 1
// baseline (408.329 us; speedup 1.0000x reference)
//
#include <hip/hip_runtime.h>
#include <math.h>

#define DEV __device__ __forceinline__

typedef float  f4v  __attribute__((ext_vector_type(4)));
typedef __bf16 b8v  __attribute__((ext_vector_type(8)));
typedef short  s8v  __attribute__((ext_vector_type(8)));

#define NEG_INF (-__builtin_huge_valf())

DEV short f2b(float f){ __bf16 h = (__bf16)f; return __builtin_bit_cast(short, h); }

DEV void gload16(const void* g, void* l){
  __builtin_amdgcn_global_load_lds((const __attribute__((address_space(1))) void*)g,
                                   (__attribute__((address_space(3))) void*)l, 16, 0, 0);
}

DEV b8v ldsf(const short* p){ return __builtin_bit_cast(b8v, *(const s8v*)p); }

DEV f4v mfma16(b8v a, b8v b, f4v c){ return __builtin_amdgcn_mfma_f32_16x16x32_bf16(a, b, c, 0, 0, 0); }

DEV void ml_update(float& m, float& l, float s){
  if (s <= m) { l += __expf(s - m); }
  else        { l = l * __expf(m - s) + 1.0f; m = s; }
}
DEV void ml_merge(float& m, float& l, float m2, float l2){
  float M = fmaxf(m, m2);
  float a = (l  > 0.0f) ? l  * __expf(m  - M) : 0.0f;
  float c = (l2 > 0.0f) ? l2 * __expf(m2 - M) : 0.0f;
  m = M; l = a + c;
}

// ---------------- f32 -> bf16 convert ----------------
__global__ void cvt_kernel(const float* __restrict__ src, short* __restrict__ dst, int n4){
  int i = blockIdx.x*256 + threadIdx.x;
  if (i >= n4) return;
  float4 v = ((const float4*)src)[i];
  short4 o = make_short4(f2b(v.x), f2b(v.y), f2b(v.z), f2b(v.w));
  ((short4*)dst)[i] = o;
}

// ---------------- LayerNorm (D=1024), f32 in -> bf16 out ----------------
__global__ __launch_bounds__(256) void ln_kernel(const float* __restrict__ x, const float* __restrict__ gg,
                                                 const float* __restrict__ bb, short* __restrict__ out){
  int row = blockIdx.x, tid = threadIdx.x;
  const float4 v = ((const float4*)(x + (size_t)row*1024))[tid];
  float s = v.x + v.y + v.z + v.w;
  #pragma unroll
  for (int off=1; off<64; off<<=1) s += __shfl_xor(s, off);
  __shared__ float red[4];
  if ((tid&63)==0) red[tid>>6] = s;
  __syncthreads();
  float mu = (red[0]+red[1]+red[2]+red[3]) * (1.0f/1024.0f);
  float d0=v.x-mu, d1=v.y-mu, d2=v.z-mu, d3=v.w-mu;
  float q = d0*d0 + d1*d1 + d2*d2 + d3*d3;
  #pragma unroll
  for (int off=1; off<64; off<<=1) q += __shfl_xor(q, off);
  __syncthreads();
  if ((tid&63)==0) red[tid>>6] = q;
  __syncthreads();
  float rs = rsqrtf((red[0]+red[1]+red[2]+red[3]) * (1.0f/1024.0f) + 1e-5f);
  float4 g4 = ((const float4*)gg)[tid];
  float4 b4 = ((const float4*)bb)[tid];
  short4 o = make_short4(f2b(d0*rs*g4.x + b4.x), f2b(d1*rs*g4.y + b4.y),
                         f2b(d2*rs*g4.z + b4.z), f2b(d3*rs*g4.w + b4.w));
  ((short4*)(out + (size_t)row*1024))[tid] = o;
}

// ---------------- GEMM: C[M,N] = A[M,K] * B[N,K]^T (bf16 in, m97 structure) ----------------
template<int OUTF32>
__global__ __launch_bounds__(256,2) void gemm_bt(const short* __restrict__ A, const short* __restrict__ B,
                                                 void* __restrict__ C, int M, int N, int K){
  __shared__ short sA[128*32];
  __shared__ short sB[128*32];
  int tid=threadIdx.x, lane=tid&63, wv=tid>>6, g=lane>>4, r=lane&15;
  int wr=wv>>1, wc=wv&1;
  int m0=blockIdx.x*128, n0=blockIdx.y*128;
  f4v z = {0.f,0.f,0.f,0.f};
  f4v acc[4][4];
  #pragma unroll
  for (int i=0;i<4;++i){
    #pragma unroll
    for (int j=0;j<4;++j) acc[i][j]=z;
  }
  int nkt = K >> 5;
  for (int kt=0; kt<nkt; ++kt){
    __syncthreads();
    #pragma unroll
    for (int i=0;i<2;++i){
      int idx = i*256 + wv*64 + lane;
      int row = idx>>2, sl = idx&3;
      gload16(A + (size_t)(m0+row)*K + kt*32 + sl*8, &sA[(i*256+wv*64)*8]);
    }
    #pragma unroll
    for (int i=0;i<2;++i){
      int idx = i*256 + wv*64 + lane;
      int row = idx>>2, sl = idx&3;
      gload16(B + (size_t)(n0+row)*K + kt*32 + sl*8, &sB[(i*256+wv*64)*8]);
    }
    __syncthreads();
    b8v af[4], bf[4];
    #pragma unroll
    for (int mf=0;mf<4;++mf) af[mf] = ldsf(&sA[(wr*64+mf*16+r)*32 + g*8]);
    #pragma unroll
    for (int nf=0;nf<4;++nf) bf[nf] = ldsf(&sB[(wc*64+nf*16+r)*32 + g*8]);
    #pragma unroll
    for (int mf=0;mf<4;++mf){
      #pragma unroll
      for (int nf=0;nf<4;++nf)
        acc[mf][nf] = mfma16(af[mf], bf[nf], acc[mf][nf]);
    }
  }
  #pragma unroll
  for (int mf=0;mf<4;++mf){
    #pragma unroll
    for (int nf=0;nf<4;++nf){
      #pragma unroll
      for (int j=0;j<4;++j){
        int m = m0 + wr*64 + mf*16 + g*4 + j;
        int n = n0 + wc*64 + nf*16 + r;
        if (OUTF32) ((float*)C)[(size_t)m*N + n] = acc[mf][nf][j];
        else        ((short*)C)[(size_t)m*N + n] = f2b(acc[mf][nf][j]);
      }
    }
  }
}

// ---------------- V (B,S,H,hd) -> Vt (B,H,hd,S) ----------------
__global__ __launch_bounds__(256) void vtrans_kernel(const short* __restrict__ v, short* __restrict__ vt){
  int bid = blockIdx.x;
  int sb = bid & 63, bh = bid >> 6;
  int b = bh >> 4, h = bh & 15;
  int s0 = sb*64;
  __shared__ short t[64][80];
  int tid = threadIdx.x;
  #pragma unroll
  for (int i=0;i<2;++i){
    int idx = tid + i*256;
    int row = idx>>3, sl = idx&7;
    *(s8v*)&t[row][sl*8] = *(const s8v*)(v + (size_t)(b*4096 + s0 + row)*1024 + h*64 + sl*8);
  }
  __syncthreads();
  int hd = tid>>2, part = tid&3;
  s8v o0, o1;
  #pragma unroll
  for (int j=0;j<8;++j){ o0[j] = t[part*16+j][hd]; o1[j] = t[part*16+8+j][hd]; }
  size_t base = (size_t)(bh*64+hd)*4096 + s0 + part*16;
  *(s8v*)(vt + base)     = o0;
  *(s8v*)(vt + base + 8) = o1;
}

// ---------------- mask pack: (attn_mask | kpm) -> bits, word per 32 s ----------------
__global__ void pack_kernel(const int* __restrict__ am, const int* __restrict__ kpm, unsigned* __restrict__ pm){
  int w = blockIdx.x*256 + threadIdx.x;   // over (B,H,Q,S/32) = 2097152
  const int4* a = (const int4*)(am + (size_t)w*32);
  unsigned bits = 0u;
  #pragma unroll
  for (int i=0;i<8;++i){
    int4 t = a[i];
    bits |= (unsigned)(t.x!=0) << (i*4+0);
    bits |= (unsigned)(t.y!=0) << (i*4+1);
    bits |= (unsigned)(t.z!=0) << (i*4+2);
    bits |= (unsigned)(t.w!=0) << (i*4+3);
  }
  int b = w >> 19, sw = w & 127;
  const int4* kp = (const int4*)(kpm + (size_t)b*4096 + sw*32);
  #pragma unroll
  for (int i=0;i<8;++i){
    int4 t = kp[i];
    bits |= (unsigned)(t.x!=0) << (i*4+0);
    bits |= (unsigned)(t.y!=0) << (i*4+1);
    bits |= (unsigned)(t.z!=0) << (i*4+2);
    bits |= (unsigned)(t.w!=0) << (i*4+3);
  }
  pm[w] = bits;
}

// ---------------- phase1a: per-(b,h,s-chunk 256) online (m,l) over masked scores ----------------
__global__ __launch_bounds__(256,2) void attn_ml_kernel(const short* __restrict__ qp, const short* __restrict__ kb,
                                                        const unsigned* __restrict__ pm, float2* __restrict__ mlc){
  int bid = blockIdx.x;             // ((b*16+h)*16 + sc)
  int sc = bid & 15, h = (bid>>4)&15, b = bid>>8;
  int bh = b*16 + h;
  int s0 = sc*256;
  __shared__ short sQ[256*64];
  __shared__ short sK[256*64];
  __shared__ unsigned sPM[256*8];
  int tid=threadIdx.x, lane=tid&63, wv=tid>>6, g=lane>>4, r=lane&15;

  #pragma unroll
  for (int i=0;i<8;++i){
    int idx = i*256 + wv*64 + lane;
    int row = idx>>3, cbs = (idx&7)^(row&7);
    gload16(qp + (size_t)(b*256 + row)*1024 + h*64 + cbs*8, &sQ[(i*256+wv*64)*8]);
  }
  #pragma unroll
  for (int i=0;i<8;++i){
    int idx = i*256 + wv*64 + lane;
    int row = idx>>3, cbs = (idx&7)^(row&7);
    gload16(kb + (size_t)(b*4096 + s0 + row)*1024 + h*64 + cbs*8, &sK[(i*256+wv*64)*8]);
  }
  #pragma unroll
  for (int i=0;i<8;++i){
    int idx = tid + i*256;
    int row = idx>>3, wd = idx&7;
    sPM[idx] = pm[(size_t)(bh*256 + row)*128 + sc*8 + wd];
  }
  __syncthreads();

  b8v a[4][2];
  #pragma unroll
  for (int mf=0;mf<4;++mf){
    #pragma unroll
    for (int ks=0;ks<2;++ks){
      int q = wv*64 + mf*16 + r;
      a[mf][ks] = ldsf(&sQ[q*64 + (((ks*4+g)^(q&7))*8)]);
    }
  }
  float mreg[4][4], lreg[4][4];
  #pragma unroll
  for (int mf=0;mf<4;++mf){
    #pragma unroll
    for (int j=0;j<4;++j){ mreg[mf][j] = NEG_INF; lreg[mf][j] = 0.f; }
  }
  f4v z = {0.f,0.f,0.f,0.f};
  #pragma unroll 4
  for (int nf=0;nf<16;++nf){
    int srow = nf*16 + r;
    b8v b0 = ldsf(&sK[srow*64 + ((g^(srow&7))*8)]);
    b8v b1 = ldsf(&sK[srow*64 + (((4+g)^(srow&7))*8)]);
    f4v acc[4];
    #pragma unroll
    for (int mf=0;mf<4;++mf){
      acc[mf] = mfma16(a[mf][0], b0, z);
      acc[mf] = mfma16(a[mf][1], b1, acc[mf]);
    }
    #pragma unroll
    for (int mf=0;mf<4;++mf){
      #pragma unroll
      for (int j=0;j<4;++j){
        int q = wv*64 + mf*16 + g*4 + j;
        unsigned wm = sPM[q*8 + (nf>>1)];
        if (!((wm >> ((nf&1)*16 + r)) & 1u))
          ml_update(mreg[mf][j], lreg[mf][j], acc[mf][j]*0.125f);
      }
    }
  }
  #pragma unroll
  for (int off=1; off<16; off<<=1){
    #pragma unroll
    for (int mf=0;mf<4;++mf){
      #pragma unroll
      for (int j=0;j<4;++j){
        float m2 = __shfl_xor(mreg[mf][j], off);
        float l2 = __shfl_xor(lreg[mf][j], off);
        ml_merge(mreg[mf][j], lreg[mf][j], m2, l2);
      }
    }
  }
  if (r == 0){
    #pragma unroll
    for (int mf=0;mf<4;++mf){
      #pragma unroll
      for (int j=0;j<4;++j){
        int q = wv*64 + mf*16 + g*4 + j;
        mlc[(size_t)bid*256 + q] = make_float2(mreg[mf][j], lreg[mf][j]);
      }
    }
  }
}

// ---------------- phase1b: combine chunks -> (m, 1/l) ----------------
__global__ void mlcomb_kernel(const float2* __restrict__ mlc, float2* __restrict__ ml){
  int row = blockIdx.x*256 + threadIdx.x;   // B*H*Q = 16384
  int q = row & 255, bh = row >> 8;
  float m = NEG_INF, l = 0.f;
  #pragma unroll
  for (int sc=0; sc<16; ++sc){
    float2 c = mlc[(size_t)(bh*16+sc)*256 + q];
    ml_merge(m, l, c.x, c.y);
  }
  float inv = (l > 0.f) ? (1.0f / l) : 0.f;
  ml[row] = make_float2(m, inv);
}

// ---------------- phase2: p = exp(s-m)/l ; mean over heads ; O += P V ----------------
__global__ __launch_bounds__(256,2) void attn_pv_kernel(const short* __restrict__ qp, const short* __restrict__ kb,
                                                        const short* __restrict__ vt, const unsigned* __restrict__ pm,
                                                        const float2* __restrict__ ml, float* __restrict__ Oacc,
                                                        float* __restrict__ out2){
  int bid = blockIdx.x;             // ((b*8+qt)*16 + sc)
  int sc = bid & 15, qt = (bid>>4)&7, b = bid>>7;
  int s0 = sc*256, q0 = qt*32;
  __shared__ short sK[256*64];      // reused as P (32x256) after the score pass
  __shared__ short sVt[64*256];
  __shared__ short sQ[32*64];
  __shared__ unsigned sPM[32*8];
  int tid=threadIdx.x, lane=tid&63, wv=tid>>6, g=lane>>4, r=lane&15;
  f4v z = {0.f,0.f,0.f,0.f};
  float macc[2][4][4];
  #pragma unroll
  for (int mf=0;mf<2;++mf){
    #pragma unroll
    for (int nf=0;nf<4;++nf){
      #pragma unroll
      for (int j=0;j<4;++j) macc[mf][nf][j] = 0.f;
    }
  }

  for (int h=0; h<16; ++h){
    int bh = b*16 + h;
    __syncthreads();
    {
      int idx = wv*64 + lane;
      int row = idx>>3, cbs = (idx&7)^(row&7);
      gload16(qp + (size_t)(b*256 + q0 + row)*1024 + h*64 + cbs*8, &sQ[(wv*64)*8]);
    }
    #pragma unroll
    for (int i=0;i<8;++i){
      int idx = i*256 + wv*64 + lane;
      int row = idx>>3, cbs = (idx&7)^(row&7);
      gload16(kb + (size_t)(b*4096 + s0 + row)*1024 + h*64 + cbs*8, &sK[(i*256+wv*64)*8]);
    }
    #pragma unroll
    for (int i=0;i<8;++i){
      int idx = i*256 + wv*64 + lane;
      int row = idx>>5, sl = idx&31, sls = sl^(row&7);
      gload16(vt + (size_t)(bh*64 + row)*4096 + s0 + sls*8, &sVt[(i*256+wv*64)*8]);
    }
    {
      int row = tid>>3, wd = tid&7;
      sPM[tid] = pm[(size_t)(bh*256 + q0 + row)*128 + sc*8 + wd];
    }
    __syncthreads();

    b8v aq[2][2];
    #pragma unroll
    for (int mf=0;mf<2;++mf){
      #pragma unroll
      for (int ks=0;ks<2;++ks){
        int q = mf*16 + r;
        aq[mf][ks] = ldsf(&sQ[q*64 + (((ks*4+g)^(q&7))*8)]);
      }
    }
    f4v accs[2][4];
    #pragma unroll
    for (int mf=0;mf<2;++mf){
      #pragma unroll
      for (int nf=0;nf<4;++nf) accs[mf][nf] = z;
    }
    #pragma unroll
    for (int nf=0;nf<4;++nf){
      int srow = wv*64 + nf*16 + r;
      b8v b0 = ldsf(&sK[srow*64 + ((g^(srow&7))*8)]);
      b8v b1 = ldsf(&sK[srow*64 + (((4+g)^(srow&7))*8)]);
      #pragma unroll
      for (int mf=0;mf<2;++mf){
        accs[mf][nf] = mfma16(aq[mf][0], b0, accs[mf][nf]);
        accs[mf][nf] = mfma16(aq[mf][1], b1, accs[mf][nf]);
      }
    }
    __syncthreads();   // done reading sK/sQ; sK becomes P

    #pragma unroll
    for (int mf=0;mf<2;++mf){
      #pragma unroll
      for (int j=0;j<4;++j){
        int ql = mf*16 + g*4 + j;
        float2 mv = ml[(size_t)bh*256 + q0 + ql];
        #pragma unroll
        for (int nf=0;nf<4;++nf){
          unsigned wm = sPM[ql*8 + wv*2 + (nf>>1)];
          unsigned mskd = (wm >> ((nf&1)*16 + r)) & 1u;
          float p = 0.f;
          if (!mskd && mv.y > 0.f) p = __expf(accs[mf][nf][j]*0.125f - mv.x) * mv.y;
          macc[mf][nf][j] += p;
          int sl_ = wv*64 + nf*16 + r;
          sK[ql*256 + (((sl_>>3)^(ql&7))*8) + (sl_&7)] = f2b(p);
        }
      }
    }
    __syncthreads();   // P visible

    f4v acco[2]; acco[0]=z; acco[1]=z;
    #pragma unroll
    for (int ks=0;ks<8;++ks){
      int vrow = wv*16 + r;
      b8v bv = ldsf(&sVt[vrow*256 + (((ks*4+g)^(vrow&7))*8)]);
      #pragma unroll
      for (int mf=0;mf<2;++mf){
        int prow = mf*16 + r;
        b8v ap = ldsf(&sK[prow*256 + (((ks*4+g)^(prow&7))*8)]);
        acco[mf] = mfma16(ap, bv, acco[mf]);
      }
    }
    #pragma unroll
    for (int mf=0;mf<2;++mf){
      #pragma unroll
      for (int j=0;j<4;++j)
        atomicAdd(&Oacc[(size_t)(b*256 + q0 + mf*16 + g*4 + j)*1024 + h*64 + wv*16 + r], acco[mf][j]);
    }
  }

  #pragma unroll
  for (int mf=0;mf<2;++mf){
    #pragma unroll
    for (int nf=0;nf<4;++nf){
      #pragma unroll
      for (int j=0;j<4;++j){
        int q = q0 + mf*16 + g*4 + j;
        int s = s0 + wv*64 + nf*16 + r;
        out2[(size_t)(b*256 + q)*4096 + s] = macc[mf][nf][j] * 0.0625f;
      }
    }
  }
}

// ---------------- launcher ----------------
extern "C" void kernel_launch(void* const* d_in, const int* in_sizes, int n_in,
                              void* d_out, int out_size, void* d_ws, size_t ws_size,
                              hipStream_t stream){
  const float* x       = (const float*)d_in[0];
  const float* queries = (const float*)d_in[1];
  const int*   am      = (const int*)d_in[2];
  const int*   kpm     = (const int*)d_in[3];
  const float* Wq      = (const float*)d_in[4];
  const float* Wk      = (const float*)d_in[5];
  const float* Wv      = (const float*)d_in[6];
  const float* Wo      = (const float*)d_in[7];
  const float* ln1g    = (const float*)d_in[8];
  const float* ln1b    = (const float*)d_in[9];
  const float* ln2g    = (const float*)d_in[10];
  const float* ln2b    = (const float*)d_in[11];
  float* out0 = (float*)d_out;
  float* out2 = out0 + (size_t)4*256*1024;
  char* ws = (char*)d_ws;

  size_t off = 0;
  auto alloc = [&](size_t bytes){ void* p = ws + off; off += (bytes + 255) & ~(size_t)255; return p; };
  short*    xn   = (short*)alloc(33554432);   // (B*S, D) bf16 ; later reused as Vt
  short*    vt   = xn;                        // (B,H,hd,S) bf16 (alias: xn dead after K/V GEMMs)
  short*    kb   = (short*)alloc(33554432);   // (B,S,D) bf16
  short*    vb   = (short*)alloc(33554432);   // (B,S,D) bf16
  short*    wqb  = (short*)alloc(2097152);
  short*    wkb  = (short*)alloc(2097152);
  short*    wvb  = (short*)alloc(2097152);
  short*    wob  = (short*)alloc(2097152);
  short*    qbf  = (short*)alloc(2097152);    // queries bf16
  short*    qpj  = (short*)alloc(2097152);    // projected q bf16
  unsigned* pmw  = (unsigned*)alloc(8388608); // packed mask bits
  float2*   mlc  = (float2*)alloc(2097152);   // per-chunk (m,l)
  float2*   mlv  = (float2*)alloc(131072);    // final (m, 1/l)
  float*    oacc = (float*)alloc(4194304);    // O accumulator f32 (B,Q,D)
  short*    onb  = (short*)alloc(2097152);    // ln2 output bf16

  hipMemsetAsync(oacc, 0, 4194304, stream);
  cvt_kernel<<<1024,256,0,stream>>>(queries, qbf, 262144);
  cvt_kernel<<<1024,256,0,stream>>>(Wq, wqb, 262144);
  cvt_kernel<<<1024,256,0,stream>>>(Wk, wkb, 262144);
  cvt_kernel<<<1024,256,0,stream>>>(Wv, wvb, 262144);
  cvt_kernel<<<1024,256,0,stream>>>(Wo, wob, 262144);
  ln_kernel<<<16384,256,0,stream>>>(x, ln1g, ln1b, xn);
  gemm_bt<0><<<dim3(128,8),256,0,stream>>>(xn, wkb, kb, 16384, 1024, 1024);
  gemm_bt<0><<<dim3(128,8),256,0,stream>>>(xn, wvb, vb, 16384, 1024, 1024);
  gemm_bt<0><<<dim3(8,8),256,0,stream>>>(qbf, wqb, qpj, 1024, 1024, 1024);
  vtrans_kernel<<<4096,256,0,stream>>>(vb, vt);
  pack_kernel<<<8192,256,0,stream>>>(am, kpm, pmw);
  attn_ml_kernel<<<1024,256,0,stream>>>(qpj, kb, pmw, mlc);
  mlcomb_kernel<<<64,256,0,stream>>>(mlc, mlv);
  attn_pv_kernel<<<512,256,0,stream>>>(qpj, kb, vt, pmw, mlv, oacc, out2);
  ln_kernel<<<1024,256,0,stream>>>(oacc, ln2g, ln2b, onb);
  gemm_bt<1><<<dim3(8,8),256,0,stream>>>(onb, wob, out0, 1024, 1024, 1024);
}

// Round 2
// 380.365 us; speedup vs baseline: 1.0735x; 1.0735x over previous
//
#include <hip/hip_runtime.h>
#include <math.h>

#define DEV __device__ __forceinline__

typedef float  f4v  __attribute__((ext_vector_type(4)));
typedef __bf16 b8v  __attribute__((ext_vector_type(8)));
typedef short  s8v  __attribute__((ext_vector_type(8)));

DEV short f2b(float f){ __bf16 h = (__bf16)f; return __builtin_bit_cast(short, h); }

DEV void gload16(const void* g, void* l){
  __builtin_amdgcn_global_load_lds((const __attribute__((address_space(1))) void*)g,
                                   (__attribute__((address_space(3))) void*)l, 16, 0, 0);
}

DEV b8v ldsf(const short* p){ return __builtin_bit_cast(b8v, *(const s8v*)p); }

DEV f4v mfma16(b8v a, b8v b, f4v c){ return __builtin_amdgcn_mfma_f32_16x16x32_bf16(a, b, c, 0, 0, 0); }

DEV void ml_merge(float& m, float& l, float m2, float l2){
  float M = fmaxf(m, m2);
  float a = (l  > 0.0f) ? l  * __expf(m  - M) : 0.0f;
  float c = (l2 > 0.0f) ? l2 * __expf(m2 - M) : 0.0f;
  m = M; l = a + c;
}

// ---------------- f32 -> bf16 convert, 5 buffers in one launch ----------------
__global__ void cvt5_kernel(const float* __restrict__ s0, const float* __restrict__ s1,
                            const float* __restrict__ s2, const float* __restrict__ s3,
                            const float* __restrict__ s4,
                            short* __restrict__ d0, short* __restrict__ d1,
                            short* __restrict__ d2, short* __restrict__ d3,
                            short* __restrict__ d4){
  int i = blockIdx.x*256 + threadIdx.x;   // 5 * 262144 float4s
  int buf = i >> 18, j = i & 262143;
  const float* s = (buf==0)?s0:(buf==1)?s1:(buf==2)?s2:(buf==3)?s3:s4;
  short*       d = (buf==0)?d0:(buf==1)?d1:(buf==2)?d2:(buf==3)?d3:d4;
  float4 v = ((const float4*)s)[j];
  ((short4*)d)[j] = make_short4(f2b(v.x), f2b(v.y), f2b(v.z), f2b(v.w));
}

// ---------------- LayerNorm (D=1024), f32 in -> bf16 out ----------------
__global__ __launch_bounds__(256) void ln_kernel(const float* __restrict__ x, const float* __restrict__ gg,
                                                 const float* __restrict__ bb, short* __restrict__ out){
  int row = blockIdx.x, tid = threadIdx.x;
  const float4 v = ((const float4*)(x + (size_t)row*1024))[tid];
  float s = v.x + v.y + v.z + v.w;
  #pragma unroll
  for (int off=1; off<64; off<<=1) s += __shfl_xor(s, off);
  __shared__ float red[4];
  if ((tid&63)==0) red[tid>>6] = s;
  __syncthreads();
  float mu = (red[0]+red[1]+red[2]+red[3]) * (1.0f/1024.0f);
  float d0=v.x-mu, d1=v.y-mu, d2=v.z-mu, d3=v.w-mu;
  float q = d0*d0 + d1*d1 + d2*d2 + d3*d3;
  #pragma unroll
  for (int off=1; off<64; off<<=1) q += __shfl_xor(q, off);
  __syncthreads();
  if ((tid&63)==0) red[tid>>6] = q;
  __syncthreads();
  float rs = rsqrtf((red[0]+red[1]+red[2]+red[3]) * (1.0f/1024.0f) + 1e-5f);
  float4 g4 = ((const float4*)gg)[tid];
  float4 b4 = ((const float4*)bb)[tid];
  short4 o = make_short4(f2b(d0*rs*g4.x + b4.x), f2b(d1*rs*g4.y + b4.y),
                         f2b(d2*rs*g4.z + b4.z), f2b(d3*rs*g4.w + b4.w));
  ((short4*)(out + (size_t)row*1024))[tid] = o;
}

// ---------------- LayerNorm fused with 16-slice sum reduce (O-partials) ----------------
__global__ __launch_bounds__(256) void ln_reduce_kernel(const float* __restrict__ opart, const float* __restrict__ gg,
                                                        const float* __restrict__ bb, short* __restrict__ out){
  int row = blockIdx.x, tid = threadIdx.x;
  float4 v = make_float4(0.f,0.f,0.f,0.f);
  #pragma unroll
  for (int sc=0; sc<16; ++sc){
    float4 t = ((const float4*)(opart + ((size_t)sc*1024 + row)*1024))[tid];
    v.x += t.x; v.y += t.y; v.z += t.z; v.w += t.w;
  }
  float s = v.x + v.y + v.z + v.w;
  #pragma unroll
  for (int off=1; off<64; off<<=1) s += __shfl_xor(s, off);
  __shared__ float red[4];
  if ((tid&63)==0) red[tid>>6] = s;
  __syncthreads();
  float mu = (red[0]+red[1]+red[2]+red[3]) * (1.0f/1024.0f);
  float d0=v.x-mu, d1=v.y-mu, d2=v.z-mu, d3=v.w-mu;
  float q = d0*d0 + d1*d1 + d2*d2 + d3*d3;
  #pragma unroll
  for (int off=1; off<64; off<<=1) q += __shfl_xor(q, off);
  __syncthreads();
  if ((tid&63)==0) red[tid>>6] = q;
  __syncthreads();
  float rs = rsqrtf((red[0]+red[1]+red[2]+red[3]) * (1.0f/1024.0f) + 1e-5f);
  float4 g4 = ((const float4*)gg)[tid];
  float4 b4 = ((const float4*)bb)[tid];
  short4 o = make_short4(f2b(d0*rs*g4.x + b4.x), f2b(d1*rs*g4.y + b4.y),
                         f2b(d2*rs*g4.z + b4.z), f2b(d3*rs*g4.w + b4.w));
  ((short4*)(out + (size_t)row*1024))[tid] = o;
}

// ---------------- GEMM: C[M,N] = A[M,K] * B[N,K]^T (bf16, m97 structure) ----------------
template<int OUTF32>
__global__ __launch_bounds__(256,2) void gemm_bt(const short* __restrict__ A, const short* __restrict__ B,
                                                 void* __restrict__ C, int M, int N, int K){
  __shared__ short sA[128*32];
  __shared__ short sB[128*32];
  int tid=threadIdx.x, lane=tid&63, wv=tid>>6, g=lane>>4, r=lane&15;
  int wr=wv>>1, wc=wv&1;
  int m0=blockIdx.x*128, n0=blockIdx.y*128;
  f4v z = {0.f,0.f,0.f,0.f};
  f4v acc[4][4];
  #pragma unroll
  for (int i=0;i<4;++i){
    #pragma unroll
    for (int j=0;j<4;++j) acc[i][j]=z;
  }
  int nkt = K >> 5;
  for (int kt=0; kt<nkt; ++kt){
    __syncthreads();
    #pragma unroll
    for (int i=0;i<2;++i){
      int idx = i*256 + wv*64 + lane;
      int row = idx>>2, sl = idx&3;
      gload16(A + (size_t)(m0+row)*K + kt*32 + sl*8, &sA[(i*256+wv*64)*8]);
    }
    #pragma unroll
    for (int i=0;i<2;++i){
      int idx = i*256 + wv*64 + lane;
      int row = idx>>2, sl = idx&3;
      gload16(B + (size_t)(n0+row)*K + kt*32 + sl*8, &sB[(i*256+wv*64)*8]);
    }
    __syncthreads();
    b8v af[4], bf[4];
    #pragma unroll
    for (int mf=0;mf<4;++mf) af[mf] = ldsf(&sA[(wr*64+mf*16+r)*32 + g*8]);
    #pragma unroll
    for (int nf=0;nf<4;++nf) bf[nf] = ldsf(&sB[(wc*64+nf*16+r)*32 + g*8]);
    #pragma unroll
    for (int mf=0;mf<4;++mf){
      #pragma unroll
      for (int nf=0;nf<4;++nf)
        acc[mf][nf] = mfma16(af[mf], bf[nf], acc[mf][nf]);
    }
  }
  #pragma unroll
  for (int mf=0;mf<4;++mf){
    #pragma unroll
    for (int nf=0;nf<4;++nf){
      #pragma unroll
      for (int j=0;j<4;++j){
        int m = m0 + wr*64 + mf*16 + g*4 + j;
        int n = n0 + wc*64 + nf*16 + r;
        if (OUTF32) ((float*)C)[(size_t)m*N + n] = acc[mf][nf][j];
        else        ((short*)C)[(size_t)m*N + n] = f2b(acc[mf][nf][j]);
      }
    }
  }
}

// ---------------- fused K+V GEMM: shared A staging, two B/C ----------------
__global__ __launch_bounds__(512,2) void gemm_dual_bt(const short* __restrict__ A, const short* __restrict__ B0,
                                                      const short* __restrict__ B1, short* __restrict__ C0,
                                                      short* __restrict__ C1, int M, int N, int K){
  __shared__ short sA[128*32];
  __shared__ short sB0[128*32];
  __shared__ short sB1[128*32];
  int tid=threadIdx.x, lane=tid&63, wv=tid>>6, g=lane>>4, r=lane&15;
  int wr=wv>>2, wc=wv&3;   // 2 x 4 wave grid; wave tile 64 x 32 per output
  int m0=blockIdx.x*128, n0=blockIdx.y*128;
  f4v z = {0.f,0.f,0.f,0.f};
  f4v a0[4][2], a1[4][2];
  #pragma unroll
  for (int i=0;i<4;++i){
    #pragma unroll
    for (int j=0;j<2;++j){ a0[i][j]=z; a1[i][j]=z; }
  }
  int row = tid>>2, sl = tid&3;
  int nkt = K >> 5;
  for (int kt=0; kt<nkt; ++kt){
    __syncthreads();
    gload16(A  + (size_t)(m0+row)*K + kt*32 + sl*8, &sA[wv*512]);
    gload16(B0 + (size_t)(n0+row)*K + kt*32 + sl*8, &sB0[wv*512]);
    gload16(B1 + (size_t)(n0+row)*K + kt*32 + sl*8, &sB1[wv*512]);
    __syncthreads();
    b8v af[4], b0[2], b1[2];
    #pragma unroll
    for (int mf=0;mf<4;++mf) af[mf] = ldsf(&sA[(wr*64+mf*16+r)*32 + g*8]);
    #pragma unroll
    for (int nf=0;nf<2;++nf){
      b0[nf] = ldsf(&sB0[(wc*32+nf*16+r)*32 + g*8]);
      b1[nf] = ldsf(&sB1[(wc*32+nf*16+r)*32 + g*8]);
    }
    #pragma unroll
    for (int mf=0;mf<4;++mf){
      #pragma unroll
      for (int nf=0;nf<2;++nf){
        a0[mf][nf] = mfma16(af[mf], b0[nf], a0[mf][nf]);
        a1[mf][nf] = mfma16(af[mf], b1[nf], a1[mf][nf]);
      }
    }
  }
  #pragma unroll
  for (int mf=0;mf<4;++mf){
    #pragma unroll
    for (int nf=0;nf<2;++nf){
      #pragma unroll
      for (int j=0;j<4;++j){
        int m = m0 + wr*64 + mf*16 + g*4 + j;
        int n = n0 + wc*32 + nf*16 + r;
        C0[(size_t)m*N + n] = f2b(a0[mf][nf][j]);
        C1[(size_t)m*N + n] = f2b(a1[mf][nf][j]);
      }
    }
  }
}

// ---------------- V (B,S,H,hd) -> Vt (B,H,hd,S) ----------------
__global__ __launch_bounds__(256) void vtrans_kernel(const short* __restrict__ v, short* __restrict__ vt){
  int bid = blockIdx.x;
  int sb = bid & 63, bh = bid >> 6;
  int b = bh >> 4, h = bh & 15;
  int s0 = sb*64;
  __shared__ short t[64][80];
  int tid = threadIdx.x;
  #pragma unroll
  for (int i=0;i<2;++i){
    int idx = tid + i*256;
    int row = idx>>3, sl = idx&7;
    *(s8v*)&t[row][sl*8] = *(const s8v*)(v + (size_t)(b*4096 + s0 + row)*1024 + h*64 + sl*8);
  }
  __syncthreads();
  int hd = tid>>2, part = tid&3;
  s8v o0, o1;
  #pragma unroll
  for (int j=0;j<8;++j){ o0[j] = t[part*16+j][hd]; o1[j] = t[part*16+8+j][hd]; }
  size_t base = (size_t)(bh*64+hd)*4096 + s0 + part*16;
  *(s8v*)(vt + base)     = o0;
  *(s8v*)(vt + base + 8) = o1;
}

// ---------------- mask pack ----------------
__global__ void pack_kernel(const int* __restrict__ am, const int* __restrict__ kpm, unsigned* __restrict__ pm){
  int w = blockIdx.x*256 + threadIdx.x;   // over (B,H,Q,S/32) = 2097152
  const int4* a = (const int4*)(am + (size_t)w*32);
  unsigned bits = 0u;
  #pragma unroll
  for (int i=0;i<8;++i){
    int4 t = a[i];
    bits |= (unsigned)(t.x!=0) << (i*4+0);
    bits |= (unsigned)(t.y!=0) << (i*4+1);
    bits |= (unsigned)(t.z!=0) << (i*4+2);
    bits |= (unsigned)(t.w!=0) << (i*4+3);
  }
  int b = w >> 19, sw = w & 127;
  const int4* kp = (const int4*)(kpm + (size_t)b*4096 + sw*32);
  #pragma unroll
  for (int i=0;i<8;++i){
    int4 t = kp[i];
    bits |= (unsigned)(t.x!=0) << (i*4+0);
    bits |= (unsigned)(t.y!=0) << (i*4+1);
    bits |= (unsigned)(t.z!=0) << (i*4+2);
    bits |= (unsigned)(t.w!=0) << (i*4+3);
  }
  pm[w] = bits;
}

// ---------------- phase1a: per-(b,h,s-chunk 256) online (m,l), branchless ----------------
__global__ __launch_bounds__(256,2) void attn_ml_kernel(const short* __restrict__ qp, const short* __restrict__ kb,
                                                        const unsigned* __restrict__ pm, float2* __restrict__ mlc){
  int bid = blockIdx.x;             // ((b*16+h)*16 + sc)
  int sc = bid & 15, h = (bid>>4)&15, b = bid>>8;
  int bh = b*16 + h;
  int s0 = sc*256;
  __shared__ short sQ[256*64];
  __shared__ short sK[256*64];
  __shared__ unsigned sPM[256*8];
  int tid=threadIdx.x, lane=tid&63, wv=tid>>6, g=lane>>4, r=lane&15;

  #pragma unroll
  for (int i=0;i<8;++i){
    int idx = i*256 + wv*64 + lane;
    int row = idx>>3, cbs = (idx&7)^(row&7);
    gload16(qp + (size_t)(b*256 + row)*1024 + h*64 + cbs*8, &sQ[(i*256+wv*64)*8]);
  }
  #pragma unroll
  for (int i=0;i<8;++i){
    int idx = i*256 + wv*64 + lane;
    int row = idx>>3, cbs = (idx&7)^(row&7);
    gload16(kb + (size_t)(b*4096 + s0 + row)*1024 + h*64 + cbs*8, &sK[(i*256+wv*64)*8]);
  }
  #pragma unroll
  for (int i=0;i<8;++i){
    int idx = tid + i*256;
    int row = idx>>3, wd = idx&7;
    sPM[idx] = pm[(size_t)(bh*256 + row)*128 + sc*8 + wd];
  }
  __syncthreads();

  b8v a[4][2];
  #pragma unroll
  for (int mf=0;mf<4;++mf){
    #pragma unroll
    for (int ks=0;ks<2;++ks){
      int q = wv*64 + mf*16 + r;
      a[mf][ks] = ldsf(&sQ[q*64 + (((ks*4+g)^(q&7))*8)]);
    }
  }
  float mreg[4][4], lreg[4][4];
  #pragma unroll
  for (int mf=0;mf<4;++mf){
    #pragma unroll
    for (int j=0;j<4;++j){ mreg[mf][j] = -3e38f; lreg[mf][j] = 0.f; }
  }
  f4v z = {0.f,0.f,0.f,0.f};
  #pragma unroll 4
  for (int nf=0;nf<16;++nf){
    int srow = nf*16 + r;
    b8v b0 = ldsf(&sK[srow*64 + ((g^(srow&7))*8)]);
    b8v b1 = ldsf(&sK[srow*64 + (((4+g)^(srow&7))*8)]);
    f4v acc[4];
    #pragma unroll
    for (int mf=0;mf<4;++mf){
      acc[mf] = mfma16(a[mf][0], b0, z);
      acc[mf] = mfma16(a[mf][1], b1, acc[mf]);
    }
    #pragma unroll
    for (int mf=0;mf<4;++mf){
      #pragma unroll
      for (int j=0;j<4;++j){
        int q = wv*64 + mf*16 + g*4 + j;
        unsigned wm = sPM[q*8 + (nf>>1)];
        bool mskd = (wm >> ((nf&1)*16 + r)) & 1u;
        float sv = acc[mf][j]*0.125f;
        float sm = mskd ? -1e30f : sv;
        float mn = fmaxf(mreg[mf][j], sm);
        float e  = mskd ? 0.f : __expf(sv - mn);
        lreg[mf][j] = lreg[mf][j]*__expf(mreg[mf][j] - mn) + e;
        mreg[mf][j] = mn;
      }
    }
  }
  #pragma unroll
  for (int off=1; off<16; off<<=1){
    #pragma unroll
    for (int mf=0;mf<4;++mf){
      #pragma unroll
      for (int j=0;j<4;++j){
        float m2 = __shfl_xor(mreg[mf][j], off);
        float l2 = __shfl_xor(lreg[mf][j], off);
        ml_merge(mreg[mf][j], lreg[mf][j], m2, l2);
      }
    }
  }
  if (r == 0){
    #pragma unroll
    for (int mf=0;mf<4;++mf){
      #pragma unroll
      for (int j=0;j<4;++j){
        int q = wv*64 + mf*16 + g*4 + j;
        mlc[(size_t)bid*256 + q] = make_float2(mreg[mf][j], lreg[mf][j]);
      }
    }
  }
}

// ---------------- phase1b: combine chunks -> (m, 1/l); dead rows -> (3e38, 0) ----------------
__global__ void mlcomb_kernel(const float2* __restrict__ mlc, float2* __restrict__ ml){
  int row = blockIdx.x*256 + threadIdx.x;   // B*H*Q = 16384
  int q = row & 255, bh = row >> 8;
  float m = -3e38f, l = 0.f;
  #pragma unroll
  for (int sc=0; sc<16; ++sc){
    float2 c = mlc[(size_t)(bh*16+sc)*256 + q];
    ml_merge(m, l, c.x, c.y);
  }
  float2 o;
  if (l > 0.f){ o = make_float2(m, 1.0f/l); } else { o = make_float2(3e38f, 0.f); }
  ml[row] = o;
}

// ---------------- phase2: p = exp(s-m)*inv ; mean over heads ; O-partials per sc ----------------
__global__ __launch_bounds__(256,2) void attn_pv_kernel(const short* __restrict__ qp, const short* __restrict__ kb,
                                                        const short* __restrict__ vt, const unsigned* __restrict__ pm,
                                                        const float2* __restrict__ ml, float* __restrict__ opart,
                                                        float* __restrict__ out2){
  int bid = blockIdx.x;             // ((b*8+qt)*16 + sc)
  int sc = bid & 15, qt = (bid>>4)&7, b = bid>>7;
  int s0 = sc*256, q0 = qt*32;
  __shared__ short sK[256*64];      // reused as P (32x256) after the score pass
  __shared__ short sVt[64*256];
  __shared__ short sQ[32*64];
  __shared__ unsigned sPM[32*8];
  int tid=threadIdx.x, lane=tid&63, wv=tid>>6, g=lane>>4, r=lane&15;
  f4v z = {0.f,0.f,0.f,0.f};
  float macc[2][4][4];
  #pragma unroll
  for (int mf=0;mf<2;++mf){
    #pragma unroll
    for (int nf=0;nf<4;++nf){
      #pragma unroll
      for (int j=0;j<4;++j) macc[mf][nf][j] = 0.f;
    }
  }

  for (int h=0; h<16; ++h){
    int bh = b*16 + h;
    __syncthreads();
    {
      int idx = wv*64 + lane;
      int row = idx>>3, cbs = (idx&7)^(row&7);
      gload16(qp + (size_t)(b*256 + q0 + row)*1024 + h*64 + cbs*8, &sQ[(wv*64)*8]);
    }
    #pragma unroll
    for (int i=0;i<8;++i){
      int idx = i*256 + wv*64 + lane;
      int row = idx>>3, cbs = (idx&7)^(row&7);
      gload16(kb + (size_t)(b*4096 + s0 + row)*1024 + h*64 + cbs*8, &sK[(i*256+wv*64)*8]);
    }
    #pragma unroll
    for (int i=0;i<8;++i){
      int idx = i*256 + wv*64 + lane;
      int row = idx>>5, sl = idx&31, sls = sl^(row&7);
      gload16(vt + (size_t)(bh*64 + row)*4096 + s0 + sls*8, &sVt[(i*256+wv*64)*8]);
    }
    {
      int row = tid>>3, wd = tid&7;
      sPM[tid] = pm[(size_t)(bh*256 + q0 + row)*128 + sc*8 + wd];
    }
    __syncthreads();

    b8v aq[2][2];
    #pragma unroll
    for (int mf=0;mf<2;++mf){
      #pragma unroll
      for (int ks=0;ks<2;++ks){
        int q = mf*16 + r;
        aq[mf][ks] = ldsf(&sQ[q*64 + (((ks*4+g)^(q&7))*8)]);
      }
    }
    f4v accs[2][4];
    #pragma unroll
    for (int mf=0;mf<2;++mf){
      #pragma unroll
      for (int nf=0;nf<4;++nf) accs[mf][nf] = z;
    }
    #pragma unroll
    for (int nf=0;nf<4;++nf){
      int srow = wv*64 + nf*16 + r;
      b8v b0 = ldsf(&sK[srow*64 + ((g^(srow&7))*8)]);
      b8v b1 = ldsf(&sK[srow*64 + (((4+g)^(srow&7))*8)]);
      #pragma unroll
      for (int mf=0;mf<2;++mf){
        accs[mf][nf] = mfma16(aq[mf][0], b0, accs[mf][nf]);
        accs[mf][nf] = mfma16(aq[mf][1], b1, accs[mf][nf]);
      }
    }
    __syncthreads();   // done reading sK/sQ; sK becomes P

    #pragma unroll
    for (int mf=0;mf<2;++mf){
      #pragma unroll
      for (int j=0;j<4;++j){
        int ql = mf*16 + g*4 + j;
        float2 mv = ml[(size_t)bh*256 + q0 + ql];
        #pragma unroll
        for (int nf=0;nf<4;++nf){
          unsigned wm = sPM[ql*8 + wv*2 + (nf>>1)];
          bool mskd = (wm >> ((nf&1)*16 + r)) & 1u;
          float p = mskd ? 0.f : __expf(accs[mf][nf][j]*0.125f - mv.x) * mv.y;
          macc[mf][nf][j] += p;
          int sl_ = wv*64 + nf*16 + r;
          sK[ql*256 + (((sl_>>3)^(ql&7))*8) + (sl_&7)] = f2b(p);
        }
      }
    }
    __syncthreads();   // P visible

    f4v acco[2]; acco[0]=z; acco[1]=z;
    #pragma unroll
    for (int ks=0;ks<8;++ks){
      int vrow = wv*16 + r;
      b8v bv = ldsf(&sVt[vrow*256 + (((ks*4+g)^(vrow&7))*8)]);
      #pragma unroll
      for (int mf=0;mf<2;++mf){
        int prow = mf*16 + r;
        b8v ap = ldsf(&sK[prow*256 + (((ks*4+g)^(prow&7))*8)]);
        acco[mf] = mfma16(ap, bv, acco[mf]);
      }
    }
    #pragma unroll
    for (int mf=0;mf<2;++mf){
      #pragma unroll
      for (int j=0;j<4;++j)
        opart[((size_t)sc*1024 + b*256 + q0 + mf*16 + g*4 + j)*1024 + h*64 + wv*16 + r] = acco[mf][j];
    }
  }

  #pragma unroll
  for (int mf=0;mf<2;++mf){
    #pragma unroll
    for (int nf=0;nf<4;++nf){
      #pragma unroll
      for (int j=0;j<4;++j){
        int q = q0 + mf*16 + g*4 + j;
        int s = s0 + wv*64 + nf*16 + r;
        out2[(size_t)(b*256 + q)*4096 + s] = macc[mf][nf][j] * 0.0625f;
      }
    }
  }
}

// ---------------- launcher ----------------
extern "C" void kernel_launch(void* const* d_in, const int* in_sizes, int n_in,
                              void* d_out, int out_size, void* d_ws, size_t ws_size,
                              hipStream_t stream){
  const float* x       = (const float*)d_in[0];
  const float* queries = (const float*)d_in[1];
  const int*   am      = (const int*)d_in[2];
  const int*   kpm     = (const int*)d_in[3];
  const float* Wq      = (const float*)d_in[4];
  const float* Wk      = (const float*)d_in[5];
  const float* Wv      = (const float*)d_in[6];
  const float* Wo      = (const float*)d_in[7];
  const float* ln1g    = (const float*)d_in[8];
  const float* ln1b    = (const float*)d_in[9];
  const float* ln2g    = (const float*)d_in[10];
  const float* ln2b    = (const float*)d_in[11];
  float* out0 = (float*)d_out;
  float* out2 = out0 + (size_t)4*256*1024;
  char* ws = (char*)d_ws;

  size_t off = 0;
  auto alloc = [&](size_t bytes){ void* p = ws + off; off += (bytes + 255) & ~(size_t)255; return p; };
  short*    xn   = (short*)alloc(33554432);   // (B*S, D) bf16 ; later reused as Vt
  short*    vt   = xn;                        // (B,H,hd,S) bf16 (alias: xn dead after K/V GEMM)
  short*    kb   = (short*)alloc(33554432);   // (B,S,D) bf16
  short*    vb   = (short*)alloc(33554432);   // (B,S,D) bf16
  short*    wqb  = (short*)alloc(2097152);
  short*    wkb  = (short*)alloc(2097152);
  short*    wvb  = (short*)alloc(2097152);
  short*    wob  = (short*)alloc(2097152);
  short*    qbf  = (short*)alloc(2097152);    // queries bf16
  short*    qpj  = (short*)alloc(2097152);    // projected q bf16
  unsigned* pmw  = (unsigned*)alloc(8388608); // packed mask bits
  float2*   mlc  = (float2*)alloc(2097152);   // per-chunk (m,l)
  float2*   mlv  = (float2*)alloc(131072);    // final (m, 1/l)
  float*    opart= (float*)alloc(67108864);   // O partials per s-chunk: [16][B*Q][1024] f32
  short*    onb  = (short*)alloc(2097152);    // ln2 output bf16

  cvt5_kernel<<<5120,256,0,stream>>>(queries, Wq, Wk, Wv, Wo, qbf, wqb, wkb, wvb, wob);
  ln_kernel<<<16384,256,0,stream>>>(x, ln1g, ln1b, xn);
  gemm_dual_bt<<<dim3(128,8),512,0,stream>>>(xn, wkb, wvb, kb, vb, 16384, 1024, 1024);
  gemm_bt<0><<<dim3(8,8),256,0,stream>>>(qbf, wqb, qpj, 1024, 1024, 1024);
  vtrans_kernel<<<4096,256,0,stream>>>(vb, vt);
  pack_kernel<<<8192,256,0,stream>>>(am, kpm, pmw);
  attn_ml_kernel<<<1024,256,0,stream>>>(qpj, kb, pmw, mlc);
  mlcomb_kernel<<<64,256,0,stream>>>(mlc, mlv);
  attn_pv_kernel<<<512,256,0,stream>>>(qpj, kb, vt, pmw, mlv, opart, out2);
  ln_reduce_kernel<<<1024,256,0,stream>>>(opart, ln2g, ln2b, onb);
  gemm_bt<1><<<dim3(8,8),256,0,stream>>>(onb, wob, out0, 1024, 1024, 1024);
}